// Round 1
// baseline (11138.332 us; speedup 1.0000x reference)
//
#include <hip/hip_runtime.h>
#include <hip/hip_bf16.h>

// Mamba-like model, fp32 baseline.
// Shapes: B=2, T=2048, H=768, L=12, V=50257. Rows M = B*T = 4096.
// Pipeline per layer: LN -> in-proj GEMM (N=1536) -> B,C proj GEMMs (N=768)
//  -> chunked scan (3 kernels, gate fused into phase3) -> out-proj GEMM with
//  fused residual. Then final LN + LM head GEMM (N=50257) into d_out.

#define H 768
#define TWO_H 1536
#define TSEQ 2048
#define BATCH 2
#define NLAYER 12
#define VOCAB 50257
#define MROWS 4096
#define CHUNK 128
#define NCHUNK 16
#define EPS 1e-5f

// ---------------------------------------------------------------- LayerNorm
__device__ inline float wave_reduce_sum(float v) {
#pragma unroll
    for (int off = 32; off > 0; off >>= 1)
        v += __shfl_xor(v, off, 64);
    return v;
}

__global__ __launch_bounds__(256) void ln_kernel(
    const float* __restrict__ x, const float* __restrict__ g,
    const float* __restrict__ b, float* __restrict__ y, int rows)
{
    int wave = threadIdx.x >> 6;
    int lane = threadIdx.x & 63;
    int row = blockIdx.x * 4 + wave;
    if (row >= rows) return;
    const float* xr = x + (long)row * H;
    float4 v[3];
    float s = 0.f, ss = 0.f;
#pragma unroll
    for (int c = 0; c < 3; c++) {
        v[c] = *(const float4*)(xr + 4 * (lane + 64 * c));
        s  += v[c].x + v[c].y + v[c].z + v[c].w;
        ss += v[c].x * v[c].x + v[c].y * v[c].y + v[c].z * v[c].z + v[c].w * v[c].w;
    }
    s = wave_reduce_sum(s);
    ss = wave_reduce_sum(ss);
    float m = s * (1.f / H);
    float var = ss * (1.f / H) - m * m;
    float sc = rsqrtf(var + EPS);
    float* yr = y + (long)row * H;
#pragma unroll
    for (int c = 0; c < 3; c++) {
        int idx = 4 * (lane + 64 * c);
        float4 gg = *(const float4*)(g + idx);
        float4 bb = *(const float4*)(b + idx);
        float4 o;
        o.x = (v[c].x - m) * sc * gg.x + bb.x;
        o.y = (v[c].y - m) * sc * gg.y + bb.y;
        o.z = (v[c].z - m) * sc * gg.z + bb.z;
        o.w = (v[c].w - m) * sc * gg.w + bb.w;
        *(float4*)(yr + idx) = o;
    }
}

// ---------------------------------------------------------------- GEMM (fp32)
// C[M,N] = A[M,K](lda) @ W[N,K]^T + bias  (+ res).  Tile 128x128, BK=8,
// 256 threads, 8x8 accumulators per thread (split as 2x 4-row x 2x 4-col
// groups 64 apart for conflict-light LDS reads and float4 stores).
template<bool HAS_RES>
__global__ __launch_bounds__(256) void gemm_tn(
    const float* __restrict__ A, int lda,
    const float* __restrict__ W,
    const float* __restrict__ bias,
    const float* __restrict__ res, int ldres,
    float* __restrict__ C, int ldc,
    int M, int N, int K)
{
    __shared__ __align__(16) float As[8][128];
    __shared__ __align__(16) float Ws[8][128];
    int tid = threadIdx.x;
    int tx = tid & 15;       // col group 0..15
    int ty = tid >> 4;       // row group 0..15
    int n0 = blockIdx.x * 128;
    int m0 = blockIdx.y * 128;

    int sr = tid >> 1;            // staging row 0..127
    int sh = (tid & 1) * 4;       // staging k offset 0 or 4

    float acc[8][8];
#pragma unroll
    for (int i = 0; i < 8; i++)
#pragma unroll
        for (int j = 0; j < 8; j++) acc[i][j] = 0.f;

    const float* Arow = A + (long)(m0 + sr) * lda + sh;
    const float* Wrow = W + (long)(n0 + sr) * K + sh;
    bool wok = (n0 + sr) < N;

    for (int k0 = 0; k0 < K; k0 += 8) {
        float4 av = *(const float4*)(Arow + k0);
        float4 wv = wok ? *(const float4*)(Wrow + k0) : make_float4(0.f, 0.f, 0.f, 0.f);
        __syncthreads();
        As[sh + 0][sr] = av.x; As[sh + 1][sr] = av.y;
        As[sh + 2][sr] = av.z; As[sh + 3][sr] = av.w;
        Ws[sh + 0][sr] = wv.x; Ws[sh + 1][sr] = wv.y;
        Ws[sh + 2][sr] = wv.z; Ws[sh + 3][sr] = wv.w;
        __syncthreads();
#pragma unroll
        for (int kk = 0; kk < 8; kk++) {
            float4 a0 = *(const float4*)&As[kk][ty * 4];
            float4 a1 = *(const float4*)&As[kk][64 + ty * 4];
            float4 b0 = *(const float4*)&Ws[kk][tx * 4];
            float4 b1 = *(const float4*)&Ws[kk][64 + tx * 4];
            float ar[8] = {a0.x, a0.y, a0.z, a0.w, a1.x, a1.y, a1.z, a1.w};
            float br[8] = {b0.x, b0.y, b0.z, b0.w, b1.x, b1.y, b1.z, b1.w};
#pragma unroll
            for (int i = 0; i < 8; i++)
#pragma unroll
                for (int j = 0; j < 8; j++)
                    acc[i][j] = fmaf(ar[i], br[j], acc[i][j]);
        }
    }

    bool cvec = (ldc & 3) == 0;
#pragma unroll
    for (int ig = 0; ig < 2; ig++)
#pragma unroll
        for (int i = 0; i < 4; i++) {
            int row = m0 + ig * 64 + ty * 4 + i;
#pragma unroll
            for (int jg = 0; jg < 2; jg++) {
                int colb = n0 + jg * 64 + tx * 4;
                if (cvec && colb + 3 < N) {
                    float4 v;
                    v.x = acc[ig * 4 + i][jg * 4 + 0] + bias[colb + 0];
                    v.y = acc[ig * 4 + i][jg * 4 + 1] + bias[colb + 1];
                    v.z = acc[ig * 4 + i][jg * 4 + 2] + bias[colb + 2];
                    v.w = acc[ig * 4 + i][jg * 4 + 3] + bias[colb + 3];
                    if (HAS_RES) {
                        const float* rr = res + (long)row * ldres + colb;
                        v.x += rr[0]; v.y += rr[1]; v.z += rr[2]; v.w += rr[3];
                    }
                    *(float4*)(C + (long)row * ldc + colb) = v;
                } else {
#pragma unroll
                    for (int j = 0; j < 4; j++) {
                        int c = colb + j;
                        if (c < N) {
                            float vv = acc[ig * 4 + i][jg * 4 + j] + bias[c];
                            if (HAS_RES) vv += res[(long)row * ldres + c];
                            C[(long)row * ldc + c] = vv;
                        }
                    }
                }
            }
        }
}

// ---------------------------------------------------------------- SSM scan
// s_t = a*s_{t-1} + b_t*x_t ; y_t = c_t*s_t + d*x_t, chunked over T.
// Thread -> (b, chunk, h) with h contiguous per block (coalesced).

__global__ __launch_bounds__(256) void scan_phase1(
    const float* __restrict__ p,     // [M,2H], x1 = cols 0..H-1
    const float* __restrict__ Bm,    // [M,H]
    const float* __restrict__ Ap,    // [H] layer slice
    float* __restrict__ st)          // [B,NCHUNK,H] chunk-local final states
{
    int tid = blockIdx.x * 256 + threadIdx.x;
    int h = tid % H;
    int rest = tid / H;
    int c = rest % NCHUNK;
    int b = rest / NCHUNK;
    float a = Ap[h];
    float s = 0.f;
    long base = (long)b * TSEQ + (long)c * CHUNK;
#pragma unroll 4
    for (int t = 0; t < CHUNK; t++) {
        long r = base + t;
        float x1 = p[r * TWO_H + h];
        float bm = Bm[r * H + h];
        s = s * a + bm * x1;
    }
    st[(rest) * H + h] = s;
}

__global__ __launch_bounds__(256) void scan_phase2(
    const float* __restrict__ st, const float* __restrict__ Ap,
    float* __restrict__ sinit)
{
    int tid = blockIdx.x * 256 + threadIdx.x;   // 0..B*H-1
    int h = tid % H;
    int b = tid / H;
    float a = Ap[h];
    float ac = a;
#pragma unroll
    for (int q = 0; q < 7; q++) ac *= ac;       // a^128 (even power, sign-safe)
    float s = 0.f;
#pragma unroll
    for (int c = 0; c < NCHUNK; c++) {
        int idx = (b * NCHUNK + c) * H + h;
        sinit[idx] = s;
        s = s * ac + st[idx];
    }
}

__global__ __launch_bounds__(256) void scan_phase3(
    const float* __restrict__ p,
    const float* __restrict__ Bm,
    const float* __restrict__ Cm,
    const float* __restrict__ Ap,
    const float* __restrict__ Dp,
    const float* __restrict__ sinit,
    float* __restrict__ g)           // gated output [M,H]
{
    int tid = blockIdx.x * 256 + threadIdx.x;
    int h = tid % H;
    int rest = tid / H;
    int c = rest % NCHUNK;
    int b = rest / NCHUNK;
    float a = Ap[h];
    float d = Dp[h];
    float s = sinit[rest * H + h];
    long base = (long)b * TSEQ + (long)c * CHUNK;
#pragma unroll 4
    for (int t = 0; t < CHUNK; t++) {
        long r = base + t;
        float x1 = p[r * TWO_H + h];
        float x2 = p[r * TWO_H + H + h];
        float bm = Bm[r * H + h];
        float cm = Cm[r * H + h];
        s = s * a + bm * x1;
        float y = cm * s + d * x1;
        float sig = 1.f / (1.f + expf(-x2));
        g[r * H + h] = y * sig;
    }
}

// ---------------------------------------------------------------- launch
extern "C" void kernel_launch(void* const* d_in, const int* in_sizes, int n_in,
                              void* d_out, int out_size, void* d_ws, size_t ws_size,
                              hipStream_t stream) {
    const float* x   = (const float*)d_in[0];
    const float* A   = (const float*)d_in[1];
    const float* D   = (const float*)d_in[2];
    const float* Bw  = (const float*)d_in[3];
    const float* Bb  = (const float*)d_in[4];
    const float* Cw  = (const float*)d_in[5];
    const float* Cb  = (const float*)d_in[6];
    const float* ng  = (const float*)d_in[7];
    const float* nb  = (const float*)d_in[8];
    const float* inW = (const float*)d_in[9];
    const float* inB = (const float*)d_in[10];
    const float* outW= (const float*)d_in[11];
    const float* outB= (const float*)d_in[12];
    const float* fng = (const float*)d_in[13];
    const float* fnb = (const float*)d_in[14];
    const float* lmW = (const float*)d_in[15];
    const float* lmB = (const float*)d_in[16];
    float* out = (float*)d_out;
    float* ws  = (float*)d_ws;

    const long NXH = (long)MROWS * H;       // 3,145,728
    float* x_cur = ws;
    float* h     = ws + NXH;                // also reused as gated output
    float* p     = ws + 2 * NXH;            // [M, 2H]
    float* Bm    = ws + 4 * NXH;
    float* Cm    = ws + 5 * NXH;
    float* st    = ws + 6 * NXH;            // [B*NCHUNK, H] = 24576 floats
    float* sinit = st + (long)BATCH * NCHUNK * H;

    hipMemcpyAsync(x_cur, x, NXH * sizeof(float), hipMemcpyDeviceToDevice, stream);

    dim3 blk(256);
    for (int l = 0; l < NLAYER; l++) {
        ln_kernel<<<MROWS / 4, blk, 0, stream>>>(x_cur, ng + l * H, nb + l * H, h, MROWS);
        gemm_tn<false><<<dim3(TWO_H / 128, MROWS / 128), blk, 0, stream>>>(
            h, H, inW + (long)l * TWO_H * H, inB + (long)l * TWO_H,
            nullptr, 0, p, TWO_H, MROWS, TWO_H, H);
        gemm_tn<false><<<dim3(H / 128, MROWS / 128), blk, 0, stream>>>(
            p, TWO_H, Bw + (long)l * H * H, Bb + (long)l * H,
            nullptr, 0, Bm, H, MROWS, H, H);
        gemm_tn<false><<<dim3(H / 128, MROWS / 128), blk, 0, stream>>>(
            p, TWO_H, Cw + (long)l * H * H, Cb + (long)l * H,
            nullptr, 0, Cm, H, MROWS, H, H);
        scan_phase1<<<BATCH * NCHUNK * H / 256, blk, 0, stream>>>(p, Bm, A + l * H, st);
        scan_phase2<<<BATCH * H / 256, blk, 0, stream>>>(st, A + l * H, sinit);
        scan_phase3<<<BATCH * NCHUNK * H / 256, blk, 0, stream>>>(
            p, Bm, Cm, A + l * H, D + l * H, sinit, h);
        gemm_tn<true><<<dim3(H / 128, MROWS / 128), blk, 0, stream>>>(
            h, H, outW + (long)l * H * H, outB + (long)l * H,
            x_cur, H, x_cur, H, MROWS, H, H);
    }
    ln_kernel<<<MROWS / 4, blk, 0, stream>>>(x_cur, fng, fnb, h, MROWS);
    gemm_tn<false><<<dim3((VOCAB + 127) / 128, MROWS / 128), blk, 0, stream>>>(
        h, H, lmW, lmB, nullptr, 0, out, VOCAB, MROWS, VOCAB, H);
}

// Round 2
// 4660.580 us; speedup vs baseline: 2.3899x; 2.3899x over previous
//
#include <hip/hip_runtime.h>
#include <hip/hip_bf16.h>

// Mamba-like model. GEMMs on MFMA via 3-term split-bf16 (near-fp32 accuracy).
// B=2, T=2048, H=768, L=12, V=50257, M=4096.

#define H 768
#define TWO_H 1536
#define TSEQ 2048
#define BATCH 2
#define NLAYER 12
#define VOCAB 50257
#define MROWS 4096
#define CHUNK 128
#define NCHUNK 16
#define EPS 1e-5f

typedef __attribute__((ext_vector_type(8))) short short8;
typedef __attribute__((ext_vector_type(4))) float f32x4;

__device__ inline unsigned short bf16_rtn(float x) {
    unsigned int u = __float_as_uint(x);
    unsigned int r = u + 0x7FFFu + ((u >> 16) & 1u);
    return (unsigned short)(r >> 16);
}
__device__ inline float bf16_tof(unsigned short h) {
    return __uint_as_float(((unsigned int)h) << 16);
}

// ---------------------------------------------------------------- LayerNorm
__device__ inline float wave_reduce_sum(float v) {
#pragma unroll
    for (int off = 32; off > 0; off >>= 1)
        v += __shfl_xor(v, off, 64);
    return v;
}

__global__ __launch_bounds__(256) void ln_kernel(
    const float* __restrict__ x, const float* __restrict__ g,
    const float* __restrict__ b, float* __restrict__ y, int rows)
{
    int wave = threadIdx.x >> 6;
    int lane = threadIdx.x & 63;
    int row = blockIdx.x * 4 + wave;
    if (row >= rows) return;
    const float* xr = x + (long)row * H;
    float4 v[3];
    float s = 0.f, ss = 0.f;
#pragma unroll
    for (int c = 0; c < 3; c++) {
        v[c] = *(const float4*)(xr + 4 * (lane + 64 * c));
        s  += v[c].x + v[c].y + v[c].z + v[c].w;
        ss += v[c].x * v[c].x + v[c].y * v[c].y + v[c].z * v[c].z + v[c].w * v[c].w;
    }
    s = wave_reduce_sum(s);
    ss = wave_reduce_sum(ss);
    float m = s * (1.f / H);
    float var = ss * (1.f / H) - m * m;
    float sc = rsqrtf(var + EPS);
    float* yr = y + (long)row * H;
#pragma unroll
    for (int c = 0; c < 3; c++) {
        int idx = 4 * (lane + 64 * c);
        float4 gg = *(const float4*)(g + idx);
        float4 bb = *(const float4*)(b + idx);
        float4 o;
        o.x = (v[c].x - m) * sc * gg.x + bb.x;
        o.y = (v[c].y - m) * sc * gg.y + bb.y;
        o.z = (v[c].z - m) * sc * gg.z + bb.z;
        o.w = (v[c].w - m) * sc * gg.w + bb.w;
        *(float4*)(yr + idx) = o;
    }
}

// ---------------------------------------------------------------- MFMA GEMM
// C[M,N] = A[M,K] @ W[N,K]^T + bias (+res), fp32 in/out, split-bf16 3-term.
// Block 128x128, BK=32, 4 waves of 64x64 (4x4 frags of 16x16x32).
// Dual-weight support: n >= nsplit uses W2/b2/C2 (for fused B,C projections).
template<bool HAS_RES>
__global__ __launch_bounds__(256) void gemm_mfma(
    const float* __restrict__ A, int lda,
    const float* __restrict__ W1, const float* __restrict__ b1,
    const float* __restrict__ W2, const float* __restrict__ b2,
    int nsplit,
    float* __restrict__ C1, float* __restrict__ C2, int ldc,
    const float* __restrict__ res, int ldres,
    int N, int K)
{
    __shared__ short8 AsH[128][4];
    __shared__ short8 AsL[128][4];
    __shared__ short8 WsH[128][4];
    __shared__ short8 WsL[128][4];

    const int tid  = threadIdx.x;
    const int lane = tid & 63;
    const int wave = tid >> 6;
    const int wrow = (wave >> 1) * 64;
    const int wcol = (wave & 1) * 64;
    const int m0 = blockIdx.x * 128;
    const int n0 = blockIdx.y * 128;

    const bool sec = (n0 >= nsplit);
    const float* Wb    = sec ? W2 : W1;
    const float* biasb = sec ? b2 : b1;
    float*       Cb    = sec ? C2 : C1;
    const int    nofs  = sec ? nsplit : 0;

    const int srow = tid >> 1;            // staging row 0..127
    const int skb  = (tid & 1) * 2;       // short8 chunk base (0 or 2)

    const float* Ap = A  + (long)(m0 + srow) * lda + (tid & 1) * 16;
    const bool wok  = (n0 + srow) < N;
    const float* Wp = Wb + (long)(n0 - nofs + srow) * K + (tid & 1) * 16;

    f32x4 acc[4][4];
#pragma unroll
    for (int i = 0; i < 4; i++)
#pragma unroll
        for (int j = 0; j < 4; j++) acc[i][j] = (f32x4)0.f;

    float4 va[4], vw[4];

    auto LOAD = [&](int k0) {
#pragma unroll
        for (int i = 0; i < 4; i++) va[i] = *(const float4*)(Ap + k0 + i * 4);
        if (wok) {
#pragma unroll
            for (int i = 0; i < 4; i++) vw[i] = *(const float4*)(Wp + k0 + i * 4);
        } else {
#pragma unroll
            for (int i = 0; i < 4; i++) vw[i] = make_float4(0.f, 0.f, 0.f, 0.f);
        }
    };

    auto STORE = [&]() {
#pragma unroll
        for (int g = 0; g < 2; g++) {
            float fa[8] = { va[2*g].x, va[2*g].y, va[2*g].z, va[2*g].w,
                            va[2*g+1].x, va[2*g+1].y, va[2*g+1].z, va[2*g+1].w };
            float fw[8] = { vw[2*g].x, vw[2*g].y, vw[2*g].z, vw[2*g].w,
                            vw[2*g+1].x, vw[2*g+1].y, vw[2*g+1].z, vw[2*g+1].w };
            short8 ahh, all_, whh, wll;
#pragma unroll
            for (int e = 0; e < 8; e++) {
                unsigned short hb = bf16_rtn(fa[e]);
                ahh[e] = (short)hb;
                all_[e] = (short)bf16_rtn(fa[e] - bf16_tof(hb));
                unsigned short wb = bf16_rtn(fw[e]);
                whh[e] = (short)wb;
                wll[e] = (short)bf16_rtn(fw[e] - bf16_tof(wb));
            }
            AsH[srow][skb + g] = ahh;
            AsL[srow][skb + g] = all_;
            WsH[srow][skb + g] = whh;
            WsL[srow][skb + g] = wll;
        }
    };

    const int lr = lane & 15;
    const int kb = lane >> 4;

    auto COMPUTE = [&]() {
        short8 ah[4], al[4], bh[4], bl[4];
#pragma unroll
        for (int i = 0; i < 4; i++) {
            ah[i] = AsH[wrow + i * 16 + lr][kb];
            al[i] = AsL[wrow + i * 16 + lr][kb];
            bh[i] = WsH[wcol + i * 16 + lr][kb];
            bl[i] = WsL[wcol + i * 16 + lr][kb];
        }
#pragma unroll
        for (int i = 0; i < 4; i++)
#pragma unroll
            for (int j = 0; j < 4; j++) {
                acc[i][j] = __builtin_amdgcn_mfma_f32_16x16x32_bf16(ah[i], bh[j], acc[i][j], 0, 0, 0);
                acc[i][j] = __builtin_amdgcn_mfma_f32_16x16x32_bf16(al[i], bh[j], acc[i][j], 0, 0, 0);
                acc[i][j] = __builtin_amdgcn_mfma_f32_16x16x32_bf16(ah[i], bl[j], acc[i][j], 0, 0, 0);
            }
    };

    const int nk = K >> 5;
    LOAD(0);
    STORE();
    __syncthreads();
    for (int ks = 1; ks < nk; ks++) {
        LOAD(ks * 32);
        COMPUTE();
        __syncthreads();
        STORE();
        __syncthreads();
    }
    COMPUTE();

    // epilogue: scalar stores, coalesced across the 16 lanes of each group
    const int lg = lane >> 4;
#pragma unroll
    for (int j = 0; j < 4; j++) {
        int gcol = n0 + wcol + j * 16 + lr;
        if (gcol >= N) continue;
        int ocol = gcol - nofs;
        float bv = biasb[ocol];
#pragma unroll
        for (int i = 0; i < 4; i++) {
#pragma unroll
            for (int r = 0; r < 4; r++) {
                long row = m0 + wrow + i * 16 + lg * 4 + r;
                float v = acc[i][j][r] + bv;
                if (HAS_RES) v += res[row * (long)ldres + ocol];
                Cb[row * (long)ldc + ocol] = v;
            }
        }
    }
}

// ---------------------------------------------------------------- SSM scan
__global__ __launch_bounds__(256) void scan_phase1(
    const float* __restrict__ p, const float* __restrict__ Bm,
    const float* __restrict__ Ap, float* __restrict__ st)
{
    int tid = blockIdx.x * 256 + threadIdx.x;
    int h = tid % H;
    int rest = tid / H;
    int c = rest % NCHUNK;
    int b = rest / NCHUNK;
    float a = Ap[h];
    float s = 0.f;
    long base = (long)b * TSEQ + (long)c * CHUNK;
#pragma unroll 4
    for (int t = 0; t < CHUNK; t++) {
        long r = base + t;
        float x1 = p[r * TWO_H + h];
        float bm = Bm[r * H + h];
        s = s * a + bm * x1;
    }
    st[rest * H + h] = s;
}

__global__ __launch_bounds__(256) void scan_phase2(
    const float* __restrict__ st, const float* __restrict__ Ap,
    float* __restrict__ sinit)
{
    int tid = blockIdx.x * 256 + threadIdx.x;   // 0..B*H-1
    int h = tid % H;
    int b = tid / H;
    float a = Ap[h];
    float ac = a;
#pragma unroll
    for (int q = 0; q < 7; q++) ac *= ac;       // a^128
    float s = 0.f;
#pragma unroll
    for (int c = 0; c < NCHUNK; c++) {
        int idx = (b * NCHUNK + c) * H + h;
        sinit[idx] = s;
        s = s * ac + st[idx];
    }
}

__global__ __launch_bounds__(256) void scan_phase3(
    const float* __restrict__ p, const float* __restrict__ Bm,
    const float* __restrict__ Cm, const float* __restrict__ Ap,
    const float* __restrict__ Dp, const float* __restrict__ sinit,
    float* __restrict__ g)
{
    int tid = blockIdx.x * 256 + threadIdx.x;
    int h = tid % H;
    int rest = tid / H;
    int c = rest % NCHUNK;
    int b = rest / NCHUNK;
    float a = Ap[h];
    float d = Dp[h];
    float s = sinit[rest * H + h];
    long base = (long)b * TSEQ + (long)c * CHUNK;
#pragma unroll 4
    for (int t = 0; t < CHUNK; t++) {
        long r = base + t;
        float x1 = p[r * TWO_H + h];
        float x2 = p[r * TWO_H + H + h];
        float bm = Bm[r * H + h];
        float cm = Cm[r * H + h];
        s = s * a + bm * x1;
        float y = cm * s + d * x1;
        float sig = 1.f / (1.f + expf(-x2));
        g[r * H + h] = y * sig;
    }
}

// ---------------------------------------------------------------- launch
extern "C" void kernel_launch(void* const* d_in, const int* in_sizes, int n_in,
                              void* d_out, int out_size, void* d_ws, size_t ws_size,
                              hipStream_t stream) {
    const float* x   = (const float*)d_in[0];
    const float* A   = (const float*)d_in[1];
    const float* D   = (const float*)d_in[2];
    const float* Bw  = (const float*)d_in[3];
    const float* Bb  = (const float*)d_in[4];
    const float* Cw  = (const float*)d_in[5];
    const float* Cb  = (const float*)d_in[6];
    const float* ng  = (const float*)d_in[7];
    const float* nb  = (const float*)d_in[8];
    const float* inW = (const float*)d_in[9];
    const float* inB = (const float*)d_in[10];
    const float* outW= (const float*)d_in[11];
    const float* outB= (const float*)d_in[12];
    const float* fng = (const float*)d_in[13];
    const float* fnb = (const float*)d_in[14];
    const float* lmW = (const float*)d_in[15];
    const float* lmB = (const float*)d_in[16];
    float* out = (float*)d_out;
    float* ws  = (float*)d_ws;

    const long NXH = (long)MROWS * H;
    float* x_cur = ws;
    float* h     = ws + NXH;
    float* p     = ws + 2 * NXH;            // [M, 2H]
    float* Bm    = ws + 4 * NXH;
    float* Cm    = ws + 5 * NXH;
    float* st    = ws + 6 * NXH;
    float* sinit = st + (long)BATCH * NCHUNK * H;

    dim3 blk(256);
    const int mt = MROWS / 128;             // 32 M-tiles (blockIdx.x fastest)
    for (int l = 0; l < NLAYER; l++) {
        const float* xin = (l == 0) ? x : x_cur;
        ln_kernel<<<MROWS / 4, blk, 0, stream>>>(xin, ng + l * H, nb + l * H, h, MROWS);
        // in-proj: [M,2H] = h @ inW^T
        gemm_mfma<false><<<dim3(mt, TWO_H / 128), blk, 0, stream>>>(
            h, H, inW + (long)l * TWO_H * H, inB + (long)l * TWO_H,
            nullptr, nullptr, TWO_H, p, nullptr, TWO_H, nullptr, 0, TWO_H, H);
        // fused B,C projections from x1 = p[:, :H]
        gemm_mfma<false><<<dim3(mt, TWO_H / 128), blk, 0, stream>>>(
            p, TWO_H, Bw + (long)l * H * H, Bb + (long)l * H,
            Cw + (long)l * H * H, Cb + (long)l * H, H,
            Bm, Cm, H, nullptr, 0, TWO_H, H);
        scan_phase1<<<BATCH * NCHUNK * H / 256, blk, 0, stream>>>(p, Bm, A + l * H, st);
        scan_phase2<<<BATCH * H / 256, blk, 0, stream>>>(st, A + l * H, sinit);
        scan_phase3<<<BATCH * NCHUNK * H / 256, blk, 0, stream>>>(
            p, Bm, Cm, A + l * H, D + l * H, sinit, h);
        // out-proj + residual -> x_cur
        gemm_mfma<true><<<dim3(mt, H / 128), blk, 0, stream>>>(
            h, H, outW + (long)l * H * H, outB + (long)l * H,
            nullptr, nullptr, H, x_cur, nullptr, H, xin, H, H, H);
    }
    ln_kernel<<<MROWS / 4, blk, 0, stream>>>(x_cur, fng, fnb, h, MROWS);
    gemm_mfma<false><<<dim3(mt, (VOCAB + 127) / 128), blk, 0, stream>>>(
        h, H, lmW, lmB, nullptr, nullptr, VOCAB,
        out, nullptr, VOCAB, nullptr, 0, VOCAB, H);
}